// Round 7
// baseline (107.140 us; speedup 1.0000x reference)
//
#include <hip/hip_runtime.h>

#define NB 4
#define VD 128
#define NSTEPS 226
#define LPR 16         // lanes per ray
#define NRAYS (NB * VD * VD)

// ---------------------------------------------------------------------------
// Per-RAY setup kernel (65536 threads): full reference-order math once per
// ray. Writes rayA = {dx,dy,dz,tmin}, rayC = {sx,sy,sz, packed(nk|ka|kb)}.
// ---------------------------------------------------------------------------
__global__ __launch_bounds__(256) void drr_ray_setup(const float* __restrict__ tp,
                                                     float4* __restrict__ rayA,
                                                     float4* __restrict__ rayC) {
    const int ray = blockIdx.x * blockDim.x + threadIdx.x;
    const int b = ray >> 14;            // 16384 rays per batch
    const int p = ray & 16383;
    const int h = p >> 7;               // u index
    const int w = p & 127;              // v index

    // ---- per-batch setup (identical op order to reference) ----
    const float* q = tp + b * 6;
    const float thx = q[0], thy = q[1], thz = q[2];
    const float t0 = -q[3];
    const float t1 = -q[4];
    const float t2 = (-q[5]) + 1000.0f;

    const float cxx = cosf(thx), sxx = sinf(thx);
    const float cyy = cosf(thy), syy = sinf(thy);
    const float czz = cosf(thz), szz = sinf(thz);

    // A = Rx @ Ry
    const float A00 = cyy;          const float A01 = 0.0f; const float A02 = syy;
    const float A10 = sxx*syy;      const float A11 = cxx;  const float A12 = (-sxx)*cyy;
    const float A20 = cxx*(-syy);   const float A21 = sxx;  const float A22 = cxx*cyy;

    // R = A @ Rz
    const float R00 = A00*czz + A01*szz;
    const float R01 = A00*(-szz) + A01*czz;
    const float R02 = A02;
    const float R10 = A10*czz + A11*szz;
    const float R11 = A10*(-szz) + A11*czz;
    const float R12 = A12;
    const float R20 = A20*czz + A21*szz;
    const float R21 = A20*(-szz) + A21*czz;
    const float R22 = A22;

    // Rt = R^T
    const float Rt00 = R00, Rt01 = R10, Rt02 = R20;
    const float Rt10 = R01, Rt11 = R11, Rt12 = R21;
    const float Rt20 = R02, Rt21 = R12, Rt22 = R22;

    const float ki00 = (float)(1.0 / (1500.0 / 1.5));
    const float ki11 = (float)(1.0 / (1500.0 / 1.5));
    const float ki02 = (float)((0.0 - 64.0) / (1500.0 / 1.5));
    const float ki12 = (float)((0.0 - 64.0) / (1500.0 / 1.5));

    const float M00 = Rt00 * ki00;
    const float M01 = Rt01 * ki11;
    const float M02 = (Rt00 * ki02 + Rt01 * ki12) + Rt02;
    const float M10 = Rt10 * ki00;
    const float M11 = Rt11 * ki11;
    const float M12 = (Rt10 * ki02 + Rt11 * ki12) + Rt12;
    const float M20 = Rt20 * ki00;
    const float M21 = Rt21 * ki11;
    const float M22 = (Rt20 * ki02 + Rt21 * ki12) + Rt22;

    const float sx = 64.0f - ((Rt00*t0 + Rt01*t1) + Rt02*t2);
    const float sy = 64.0f - ((Rt10*t0 + Rt11*t1) + Rt12*t2);
    const float sz = 64.0f - ((Rt20*t0 + Rt21*t1) + Rt22*t2);

    // ---- per-ray direction / slab ----
    const float u = (float)h + 0.5f;
    const float v = (float)w + 0.5f;

    float dx = (M00*u + M01*v) + M02;
    float dy = (M10*u + M11*v) + M12;
    float dz = (M20*u + M21*v) + M22;
    const float phys = sqrtf((dx*dx + dy*dy) + dz*dz);
    dx /= phys; dy /= phys; dz /= phys;

    const float sdx = (fabsf(dx) < 1e-8f) ? 1e-8f : dx;
    const float sdy = (fabsf(dy) < 1e-8f) ? 1e-8f : dy;
    const float sdz = (fabsf(dz) < 1e-8f) ? 1e-8f : dz;

    const float t0x = (0.0f - sx) / sdx, t1x = (128.0f - sx) / sdx;
    const float t0y = (0.0f - sy) / sdy, t1y = (128.0f - sy) / sdy;
    const float t0z = (0.0f - sz) / sdz, t1z = (128.0f - sz) / sdz;

    float tmin = fmaxf(fmaxf(fminf(t0x, t1x), fminf(t0y, t1y)), fminf(t0z, t1z));
    tmin = fmaxf(tmin, 0.0f);
    const float tmax = fminf(fminf(fmaxf(t0x, t1x), fmaxf(t0y, t1y)), fmaxf(t0z, t1z));

    // ---- exact trip count: #k in [0,NSTEPS) with tmin + (k+0.5) < tmax ----
    int nk = (int)ceilf(tmax - tmin - 0.5f);
    nk = max(0, min(NSTEPS, nk));
    while (nk < NSTEPS && (tmin + ((float)nk + 0.5f) < tmax)) ++nk;
    while (nk > 0 && !(tmin + ((float)(nk - 1) + 0.5f) < tmax)) --nk;

    // ---- conservative interior step range [ka, kb): all 8 corners in-bounds
    // with margin (px,py,pz in [0.5,126.5]); validated bit-exact vs checked path.
    const float rx = t1x - t0x, ry = t1y - t0y, rz = t1z - t0z;
    const float ax0 = t0x + 0.00390625f * rx, ax1 = t0x + 0.98828125f * rx;
    const float ay0 = t0y + 0.00390625f * ry, ay1 = t0y + 0.98828125f * ry;
    const float az0 = t0z + 0.00390625f * rz, az1 = t0z + 0.98828125f * rz;
    const float tin  = fmaxf(fmaxf(fminf(ax0, ax1), fminf(ay0, ay1)), fminf(az0, az1));
    const float tout = fminf(fminf(fmaxf(ax0, ax1), fmaxf(ay0, ay1)), fmaxf(az0, az1));
    int ka = (int)ceilf(tin - tmin - 0.5f) + 1;
    int kb = (int)floorf(tout - tmin - 0.5f) - 1;
    ka = max(0, min(nk, ka));
    kb = max(ka, min(nk, kb));

    rayA[ray] = make_float4(dx, dy, dz, tmin);
    const int packed = nk | (ka << 8) | (kb << 16);
    rayC[ray] = make_float4(sx, sy, sz, __int_as_float(packed));
}

// ---------------------------------------------------------------------------
// Main kernel: LPR lanes per ray, lane j marches steps j, j+LPR, ...
// Split march: [0,ka) checked / [ka,kb) interior 4-wide-unrolled lerp fast
// path with dual accumulators (32 gathers in flight) / [kb,nk) checked.
// ---------------------------------------------------------------------------
__global__ __launch_bounds__(256) void drr_proj_kernel(const float* __restrict__ vol,
                                                       const float4* __restrict__ rayA,
                                                       const float4* __restrict__ rayC,
                                                       float* __restrict__ out) {
    const int gtid = blockIdx.x * blockDim.x + threadIdx.x;
    const int ray   = gtid >> 4;
    const int phase = gtid & (LPR - 1);
    const int b = ray >> 14;

    const float4 A = rayA[ray];
    const float4 C = rayC[ray];
    const float dx = A.x, dy = A.y, dz = A.z, tmin = A.w;
    const float sx = C.x, sy = C.y, sz = C.z;
    const int packed = __float_as_int(C.w);
    const int nk = packed & 255;
    const int ka = (packed >> 8) & 255;
    const int kb = (packed >> 16) & 255;

    const int myn = (nk > phase) ? ((nk - phase + LPR - 1) >> 4) : 0;
    int iA = (ka > phase) ? ((ka - phase + LPR - 1) >> 4) : 0;  iA = min(iA, myn);
    int iB = (kb > phase) ? ((kb - phase + LPR - 1) >> 4) : 0;  iB = min(max(iB, iA), myn);

    const float* volb = vol + (size_t)b * (VD * VD * VD);
    float acc = 0.0f;

    // checked body, exact reference corner order (boundary steps only)
    auto slow_step = [&](int k) {
        const float ts = tmin + ((float)k + 0.5f);
        const float px = sx + ts * dx;
        const float py = sy + ts * dy;
        const float pz = sz + ts * dz;
        const float fx = floorf(px), fy = floorf(py), fz = floorf(pz);
        const int ix = (int)fx, iy = (int)fy, iz = (int)fz;
        const float frx = px - fx, fry = py - fy, frz = pz - fz;
        const float wx1 = frx, wx0 = 1.0f - frx;
        const float wy1 = fry, wy0 = 1.0f - fry;
        const float wz1 = frz, wz0 = 1.0f - frz;
        const int ix1 = ix + 1, iy1 = iy + 1, iz1 = iz + 1;
        const bool vx0 = (ix  >= 0) && (ix  < VD);
        const bool vx1 = (ix1 >= 0) && (ix1 < VD);
        const bool vy0 = (iy  >= 0) && (iy  < VD);
        const bool vy1 = (iy1 >= 0) && (iy1 < VD);
        const bool vz0 = (iz  >= 0) && (iz  < VD);
        const bool vz1 = (iz1 >= 0) && (iz1 < VD);
        const int cx0 = min(max(ix,  0), VD - 1), cx1 = min(max(ix1, 0), VD - 1);
        const int cy0 = min(max(iy,  0), VD - 1), cy1 = min(max(iy1, 0), VD - 1);
        const int cz0 = min(max(iz,  0), VD - 1), cz1 = min(max(iz1, 0), VD - 1);
        const int bx0 = cx0 * (VD * VD), bx1 = cx1 * (VD * VD);
        const int by0 = cy0 * VD,        by1 = cy1 * VD;
        float smp = 0.0f;
        smp += ((vx0 && vy0 && vz0) ? volb[bx0 + by0 + cz0] : 0.0f) * ((wx0 * wy0) * wz0);
        smp += ((vx0 && vy0 && vz1) ? volb[bx0 + by0 + cz1] : 0.0f) * ((wx0 * wy0) * wz1);
        smp += ((vx0 && vy1 && vz0) ? volb[bx0 + by1 + cz0] : 0.0f) * ((wx0 * wy1) * wz0);
        smp += ((vx0 && vy1 && vz1) ? volb[bx0 + by1 + cz1] : 0.0f) * ((wx0 * wy1) * wz1);
        smp += ((vx1 && vy0 && vz0) ? volb[bx1 + by0 + cz0] : 0.0f) * ((wx1 * wy0) * wz0);
        smp += ((vx1 && vy0 && vz1) ? volb[bx1 + by0 + cz1] : 0.0f) * ((wx1 * wy0) * wz1);
        smp += ((vx1 && vy1 && vz0) ? volb[bx1 + by1 + cz0] : 0.0f) * ((wx1 * wy1) * wz0);
        smp += ((vx1 && vy1 && vz1) ? volb[bx1 + by1 + cz1] : 0.0f) * ((wx1 * wy1) * wz1);
        acc += smp;
    };

    // interior fast sample: 3-level lerp, no bounds handling
    auto fast_sample = [&](int i) -> float {
        const int k = phase + (i << 4);
        const float ts = tmin + ((float)k + 0.5f);
        const float px = sx + ts * dx;
        const float py = sy + ts * dy;
        const float pz = sz + ts * dz;
        const float fx = floorf(px), fy = floorf(py), fz = floorf(pz);
        const int ix = (int)fx, iy = (int)fy, iz = (int)fz;
        const float frx = px - fx, fry = py - fy, frz = pz - fz;

        const float* pa = volb + (((ix << 7) + iy) << 7) + iz;
        const float* pb = pa + VD * VD;
        const float v000 = pa[0],      v001 = pa[1];
        const float v010 = pa[VD],     v011 = pa[VD + 1];
        const float v100 = pb[0],      v101 = pb[1];
        const float v110 = pb[VD],     v111 = pb[VD + 1];

        const float c00 = v000 + frz * (v001 - v000);
        const float c01 = v010 + frz * (v011 - v010);
        const float c10 = v100 + frz * (v101 - v100);
        const float c11 = v110 + frz * (v111 - v110);
        const float c0  = c00 + fry * (c01 - c00);
        const float c1  = c10 + fry * (c11 - c10);
        return c0 + frx * (c1 - c0);
    };

    #pragma unroll 1
    for (int i = 0; i < iA; ++i) slow_step(phase + (i << 4));

    // 4-wide manual unroll, two independent accumulators (break dep chains,
    // 32 gathers in flight per lane)
    {
        float acc0 = 0.0f, acc1 = 0.0f;
        int i = iA;
        #pragma unroll 1
        for (; i + 4 <= iB; i += 4) {
            const float s0 = fast_sample(i);
            const float s1 = fast_sample(i + 1);
            const float s2 = fast_sample(i + 2);
            const float s3 = fast_sample(i + 3);
            acc0 += (s0 + s1);
            acc1 += (s2 + s3);
        }
        #pragma unroll 1
        for (; i < iB; ++i) acc0 += fast_sample(i);
        acc += (acc0 + acc1);
    }

    #pragma unroll 1
    for (int i = iB; i < myn; ++i) slow_step(phase + (i << 4));

    // 16-lane butterfly reduce within the ray's lane group
    acc += __shfl_xor(acc, 1, 64);
    acc += __shfl_xor(acc, 2, 64);
    acc += __shfl_xor(acc, 4, 64);
    acc += __shfl_xor(acc, 8, 64);

    if (phase == 0) out[ray] = acc / 10.0f;
}

extern "C" void kernel_launch(void* const* d_in, const int* in_sizes, int n_in,
                              void* d_out, int out_size, void* d_ws, size_t ws_size,
                              hipStream_t stream) {
    const float* vol = (const float*)d_in[0];   // (4,1,128,128,128) f32
    const float* tp  = (const float*)d_in[1];   // (4,6) f32
    float* out = (float*)d_out;                 // (4,1,128,128) f32

    float4* rayA = (float4*)d_ws;                       // [NRAYS]
    float4* rayC = (float4*)((char*)d_ws + NRAYS * 16); // [NRAYS]

    hipLaunchKernelGGL(drr_ray_setup, dim3(NRAYS / 256), dim3(256), 0, stream,
                       tp, rayA, rayC);

    const int total_threads = NRAYS * LPR;   // 1048576
    hipLaunchKernelGGL(drr_proj_kernel, dim3(total_threads / 256), dim3(256), 0, stream,
                       vol, rayA, rayC, out);
}

// Round 9
// 102.750 us; speedup vs baseline: 1.0427x; 1.0427x over previous
//
#include <hip/hip_runtime.h>

#define NB 4
#define VD 128
#define NSTEPS 226
#define LPR 16         // lanes per ray
#define NRAYS (NB * VD * VD)

// ---------------------------------------------------------------------------
// Per-RAY setup kernel (65536 threads): full reference-order math once per
// ray. Writes rayA = {dx,dy,dz,tmin}, rayC = {sx,sy,sz, packed(nk|ka|kb)}.
// ---------------------------------------------------------------------------
__global__ __launch_bounds__(256) void drr_ray_setup(const float* __restrict__ tp,
                                                     float4* __restrict__ rayA,
                                                     float4* __restrict__ rayC) {
    const int ray = blockIdx.x * blockDim.x + threadIdx.x;
    const int b = ray >> 14;            // 16384 rays per batch
    const int p = ray & 16383;
    const int h = p >> 7;               // u index
    const int w = p & 127;              // v index

    // ---- per-batch setup (identical op order to reference) ----
    const float* q = tp + b * 6;
    const float thx = q[0], thy = q[1], thz = q[2];
    const float t0 = -q[3];
    const float t1 = -q[4];
    const float t2 = (-q[5]) + 1000.0f;

    const float cxx = cosf(thx), sxx = sinf(thx);
    const float cyy = cosf(thy), syy = sinf(thy);
    const float czz = cosf(thz), szz = sinf(thz);

    // A = Rx @ Ry
    const float A00 = cyy;          const float A01 = 0.0f; const float A02 = syy;
    const float A10 = sxx*syy;      const float A11 = cxx;  const float A12 = (-sxx)*cyy;
    const float A20 = cxx*(-syy);   const float A21 = sxx;  const float A22 = cxx*cyy;

    // R = A @ Rz
    const float R00 = A00*czz + A01*szz;
    const float R01 = A00*(-szz) + A01*czz;
    const float R02 = A02;
    const float R10 = A10*czz + A11*szz;
    const float R11 = A10*(-szz) + A11*czz;
    const float R12 = A12;
    const float R20 = A20*czz + A21*szz;
    const float R21 = A20*(-szz) + A21*czz;
    const float R22 = A22;

    // Rt = R^T
    const float Rt00 = R00, Rt01 = R10, Rt02 = R20;
    const float Rt10 = R01, Rt11 = R11, Rt12 = R21;
    const float Rt20 = R02, Rt21 = R12, Rt22 = R22;

    const float ki00 = (float)(1.0 / (1500.0 / 1.5));
    const float ki11 = (float)(1.0 / (1500.0 / 1.5));
    const float ki02 = (float)((0.0 - 64.0) / (1500.0 / 1.5));
    const float ki12 = (float)((0.0 - 64.0) / (1500.0 / 1.5));

    const float M00 = Rt00 * ki00;
    const float M01 = Rt01 * ki11;
    const float M02 = (Rt00 * ki02 + Rt01 * ki12) + Rt02;
    const float M10 = Rt10 * ki00;
    const float M11 = Rt11 * ki11;
    const float M12 = (Rt10 * ki02 + Rt11 * ki12) + Rt12;
    const float M20 = Rt20 * ki00;
    const float M21 = Rt21 * ki11;
    const float M22 = (Rt20 * ki02 + Rt21 * ki12) + Rt22;

    const float sx = 64.0f - ((Rt00*t0 + Rt01*t1) + Rt02*t2);
    const float sy = 64.0f - ((Rt10*t0 + Rt11*t1) + Rt12*t2);
    const float sz = 64.0f - ((Rt20*t0 + Rt21*t1) + Rt22*t2);

    // ---- per-ray direction / slab ----
    const float u = (float)h + 0.5f;
    const float v = (float)w + 0.5f;

    float dx = (M00*u + M01*v) + M02;
    float dy = (M10*u + M11*v) + M12;
    float dz = (M20*u + M21*v) + M22;
    const float phys = sqrtf((dx*dx + dy*dy) + dz*dz);
    dx /= phys; dy /= phys; dz /= phys;

    const float sdx = (fabsf(dx) < 1e-8f) ? 1e-8f : dx;
    const float sdy = (fabsf(dy) < 1e-8f) ? 1e-8f : dy;
    const float sdz = (fabsf(dz) < 1e-8f) ? 1e-8f : dz;

    const float t0x = (0.0f - sx) / sdx, t1x = (128.0f - sx) / sdx;
    const float t0y = (0.0f - sy) / sdy, t1y = (128.0f - sy) / sdy;
    const float t0z = (0.0f - sz) / sdz, t1z = (128.0f - sz) / sdz;

    float tmin = fmaxf(fmaxf(fminf(t0x, t1x), fminf(t0y, t1y)), fminf(t0z, t1z));
    tmin = fmaxf(tmin, 0.0f);
    const float tmax = fminf(fminf(fmaxf(t0x, t1x), fmaxf(t0y, t1y)), fmaxf(t0z, t1z));

    // ---- exact trip count: #k in [0,NSTEPS) with tmin + (k+0.5) < tmax ----
    int nk = (int)ceilf(tmax - tmin - 0.5f);
    nk = max(0, min(NSTEPS, nk));
    while (nk < NSTEPS && (tmin + ((float)nk + 0.5f) < tmax)) ++nk;
    while (nk > 0 && !(tmin + ((float)(nk - 1) + 0.5f) < tmax)) --nk;

    // ---- conservative interior step range [ka, kb): all 8 corners in-bounds
    // with margin (px,py,pz in [0.5,126.5]); validated bit-exact vs checked path.
    const float rx = t1x - t0x, ry = t1y - t0y, rz = t1z - t0z;
    const float ax0 = t0x + 0.00390625f * rx, ax1 = t0x + 0.98828125f * rx;
    const float ay0 = t0y + 0.00390625f * ry, ay1 = t0y + 0.98828125f * ry;
    const float az0 = t0z + 0.00390625f * rz, az1 = t0z + 0.98828125f * rz;
    const float tin  = fmaxf(fmaxf(fminf(ax0, ax1), fminf(ay0, ay1)), fminf(az0, az1));
    const float tout = fminf(fminf(fmaxf(ax0, ax1), fmaxf(ay0, ay1)), fmaxf(az0, az1));
    int ka = (int)ceilf(tin - tmin - 0.5f) + 1;
    int kb = (int)floorf(tout - tmin - 0.5f) - 1;
    ka = max(0, min(nk, ka));
    kb = max(ka, min(nk, kb));

    rayA[ray] = make_float4(dx, dy, dz, tmin);
    const int packed = nk | (ka << 8) | (kb << 16);
    rayC[ray] = make_float4(sx, sy, sz, __int_as_float(packed));
}

// ---------------------------------------------------------------------------
// Main kernel: LPR lanes per ray, lane j marches steps j, j+LPR, ...
// Split march: [0,ka) checked / [ka,kb) interior lerp fast path with
// dwordx2 z-pair loads (4 addresses/sample instead of 8) / [kb,nk) checked.
// ---------------------------------------------------------------------------
__global__ __launch_bounds__(256) void drr_proj_kernel(const float* __restrict__ vol,
                                                       const float4* __restrict__ rayA,
                                                       const float4* __restrict__ rayC,
                                                       float* __restrict__ out) {
    const int gtid = blockIdx.x * blockDim.x + threadIdx.x;
    const int ray   = gtid >> 4;
    const int phase = gtid & (LPR - 1);
    const int b = ray >> 14;

    const float4 A = rayA[ray];
    const float4 C = rayC[ray];
    const float dx = A.x, dy = A.y, dz = A.z, tmin = A.w;
    const float sx = C.x, sy = C.y, sz = C.z;
    const int packed = __float_as_int(C.w);
    const int nk = packed & 255;
    const int ka = (packed >> 8) & 255;
    const int kb = (packed >> 16) & 255;

    const int myn = (nk > phase) ? ((nk - phase + LPR - 1) >> 4) : 0;
    int iA = (ka > phase) ? ((ka - phase + LPR - 1) >> 4) : 0;  iA = min(iA, myn);
    int iB = (kb > phase) ? ((kb - phase + LPR - 1) >> 4) : 0;  iB = min(max(iB, iA), myn);

    const float* volb = vol + (size_t)b * (VD * VD * VD);
    float acc = 0.0f;

    // checked body, exact reference corner order (boundary steps only)
    auto slow_step = [&](int k) {
        const float ts = tmin + ((float)k + 0.5f);
        const float px = sx + ts * dx;
        const float py = sy + ts * dy;
        const float pz = sz + ts * dz;
        const float fx = floorf(px), fy = floorf(py), fz = floorf(pz);
        const int ix = (int)fx, iy = (int)fy, iz = (int)fz;
        const float frx = px - fx, fry = py - fy, frz = pz - fz;
        const float wx1 = frx, wx0 = 1.0f - frx;
        const float wy1 = fry, wy0 = 1.0f - fry;
        const float wz1 = frz, wz0 = 1.0f - frz;
        const int ix1 = ix + 1, iy1 = iy + 1, iz1 = iz + 1;
        const bool vx0 = (ix  >= 0) && (ix  < VD);
        const bool vx1 = (ix1 >= 0) && (ix1 < VD);
        const bool vy0 = (iy  >= 0) && (iy  < VD);
        const bool vy1 = (iy1 >= 0) && (iy1 < VD);
        const bool vz0 = (iz  >= 0) && (iz  < VD);
        const bool vz1 = (iz1 >= 0) && (iz1 < VD);
        const int cx0 = min(max(ix,  0), VD - 1), cx1 = min(max(ix1, 0), VD - 1);
        const int cy0 = min(max(iy,  0), VD - 1), cy1 = min(max(iy1, 0), VD - 1);
        const int cz0 = min(max(iz,  0), VD - 1), cz1 = min(max(iz1, 0), VD - 1);
        const int bx0 = cx0 * (VD * VD), bx1 = cx1 * (VD * VD);
        const int by0 = cy0 * VD,        by1 = cy1 * VD;
        float smp = 0.0f;
        smp += ((vx0 && vy0 && vz0) ? volb[bx0 + by0 + cz0] : 0.0f) * ((wx0 * wy0) * wz0);
        smp += ((vx0 && vy0 && vz1) ? volb[bx0 + by0 + cz1] : 0.0f) * ((wx0 * wy0) * wz1);
        smp += ((vx0 && vy1 && vz0) ? volb[bx0 + by1 + cz0] : 0.0f) * ((wx0 * wy1) * wz0);
        smp += ((vx0 && vy1 && vz1) ? volb[bx0 + by1 + cz1] : 0.0f) * ((wx0 * wy1) * wz1);
        smp += ((vx1 && vy0 && vz0) ? volb[bx1 + by0 + cz0] : 0.0f) * ((wx1 * wy0) * wz0);
        smp += ((vx1 && vy0 && vz1) ? volb[bx1 + by0 + cz1] : 0.0f) * ((wx1 * wy0) * wz1);
        smp += ((vx1 && vy1 && vz0) ? volb[bx1 + by1 + cz0] : 0.0f) * ((wx1 * wy1) * wz0);
        smp += ((vx1 && vy1 && vz1) ? volb[bx1 + by1 + cz1] : 0.0f) * ((wx1 * wy1) * wz1);
        acc += smp;
    };

    #pragma unroll 1
    for (int i = 0; i < iA; ++i) slow_step(phase + (i << 4));

    // interior fast loop: z-pair dwordx2 loads (4 addresses/sample), 3-level lerp
    #pragma unroll 2
    for (int i = iA; i < iB; ++i) {
        const int k = phase + (i << 4);
        const float ts = tmin + ((float)k + 0.5f);
        const float px = sx + ts * dx;
        const float py = sy + ts * dy;
        const float pz = sz + ts * dz;
        const float fx = floorf(px), fy = floorf(py), fz = floorf(pz);
        const int ix = (int)fx, iy = (int)fy, iz = (int)fz;
        const float frx = px - fx, fry = py - fy, frz = pz - fz;

        const float* pa = volb + (((ix << 7) + iy) << 7) + iz;
        const float* pb = pa + VD * VD;
        // (v[z], v[z+1]) pairs as single 8-byte loads (4-byte aligned is fine
        // on gfx9+ unaligned-access mode); values bit-identical to scalar loads
        const float2 r00 = *(const float2*)(pa);        // v000, v001
        const float2 r01 = *(const float2*)(pa + VD);   // v010, v011
        const float2 r10 = *(const float2*)(pb);        // v100, v101
        const float2 r11 = *(const float2*)(pb + VD);   // v110, v111

        const float c00 = r00.x + frz * (r00.y - r00.x);
        const float c01 = r01.x + frz * (r01.y - r01.x);
        const float c10 = r10.x + frz * (r10.y - r10.x);
        const float c11 = r11.x + frz * (r11.y - r11.x);
        const float c0  = c00 + fry * (c01 - c00);
        const float c1  = c10 + fry * (c11 - c10);
        acc += c0 + frx * (c1 - c0);
    }

    #pragma unroll 1
    for (int i = iB; i < myn; ++i) slow_step(phase + (i << 4));

    // 16-lane butterfly reduce within the ray's lane group
    acc += __shfl_xor(acc, 1, 64);
    acc += __shfl_xor(acc, 2, 64);
    acc += __shfl_xor(acc, 4, 64);
    acc += __shfl_xor(acc, 8, 64);

    if (phase == 0) out[ray] = acc / 10.0f;
}

extern "C" void kernel_launch(void* const* d_in, const int* in_sizes, int n_in,
                              void* d_out, int out_size, void* d_ws, size_t ws_size,
                              hipStream_t stream) {
    const float* vol = (const float*)d_in[0];   // (4,1,128,128,128) f32
    const float* tp  = (const float*)d_in[1];   // (4,6) f32
    float* out = (float*)d_out;                 // (4,1,128,128) f32

    float4* rayA = (float4*)d_ws;                       // [NRAYS]
    float4* rayC = (float4*)((char*)d_ws + NRAYS * 16); // [NRAYS]

    hipLaunchKernelGGL(drr_ray_setup, dim3(NRAYS / 256), dim3(256), 0, stream,
                       tp, rayA, rayC);

    const int total_threads = NRAYS * LPR;   // 1048576
    hipLaunchKernelGGL(drr_proj_kernel, dim3(total_threads / 256), dim3(256), 0, stream,
                       vol, rayA, rayC, out);
}